// Round 1
// baseline (1139.649 us; speedup 1.0000x reference)
//
#include <hip/hip_runtime.h>
#include <math.h>

// Shapes: B=8, H=W=64, C=256, HEADS=8, d=32, WS=8, SS=4, K=9
// NTOK = 8*64*64 = 32768 tokens; 512 windows of 64 tokens.

#define NFLOAT_BUF 8388608  // 32768*256

// ---------------------------------------------------------------------------
// K0: transpose dsc_weight (O=256, I=256, K=9) -> wT[k][i][o]
// ---------------------------------------------------------------------------
__global__ __launch_bounds__(256) void transpose_w_kernel(const float* __restrict__ w,
                                                          float* __restrict__ wT) {
    int t = blockIdx.x * 256 + threadIdx.x;   // < 9*256*256 = 589824
    int o = t & 255;
    int i = (t >> 8) & 255;
    int k = t >> 16;
    wT[t] = w[(o * 256 + i) * 9 + k];
}

// ---------------------------------------------------------------------------
// K4: snake coordinate map (y only; x is analytic integer) -> ymap[b][wd*9+k][hd]
// ---------------------------------------------------------------------------
__global__ __launch_bounds__(256) void ymap_kernel(const float* __restrict__ offset,
                                                   float* __restrict__ ymap) {
    int t = blockIdx.x * 256 + threadIdx.x;   // < 32768
    int hd = t & 63;
    int wd = (t >> 6) & 63;
    int b  = t >> 12;
    const float* op = offset + ((size_t)(b * 18) * 64 + wd) * 64 + hd;
    float yo[9];
    #pragma unroll
    for (int k = 0; k < 9; ++k) yo[k] = op[(size_t)k * 4096];
    float cum[9];
    cum[4] = 0.0f;
    float s = 0.0f;
    // down: cum[j] = sum_{t=j..3} yo[t], accumulated in order y3,y2,y1,y0 (matches ref cumsum)
    for (int j = 3; j >= 0; --j) { s += yo[j]; cum[j] = s; }
    s = 0.0f;
    for (int j = 5; j < 9; ++j) { s += yo[j]; cum[j] = s; }
    float wdf = (float)wd;
    float* yp = ymap + ((size_t)(b * 576 + wd * 9)) * 64 + hd;
    #pragma unroll
    for (int k = 0; k < 9; ++k) yp[(size_t)k * 64] = wdf + cum[k];
}

// ---------------------------------------------------------------------------
// K1: QKV GEMM. M=32768 (windowed+rolled tokens), N=768, K=256.
// A[m][k] gathered from x via roll+window mapping (rows contiguous in k).
// out = A @ qkv_w^T + qkv_b ; q rows (f<256) scaled by 32^-0.5.
// Writes q/k/v as [window(512)][head(8)][l(64)][d(32)].
// ---------------------------------------------------------------------------
__global__ __launch_bounds__(256) void qkv_gemm_kernel(
    const float* __restrict__ x, const float* __restrict__ qkv_w,
    const float* __restrict__ qkv_b,
    float* __restrict__ qb, float* __restrict__ kb, float* __restrict__ vb) {
    __shared__ float As[64][17];
    __shared__ float Bs[16][65];
    int tid = threadIdx.x;
    int tx = tid & 15, ty = tid >> 4;
    int tx4 = tx * 4, ty4 = ty * 4;
    int f0 = blockIdx.x * 64;
    int m0 = blockIdx.y * 64;

    // A-load mapping (this thread always loads the same row, different k-chunks)
    int ai = tid >> 2;          // 0..63 row in tile
    int aj = (tid & 3) * 4;     // 0,4,8,12
    int m  = m0 + ai;
    int gw = m >> 6, l = m & 63;
    int b  = gw >> 6, win = gw & 63;
    int rh = ((win >> 3) << 3) + (l >> 3);
    int rw = ((win & 7) << 3) + (l & 7);
    int sh = (rh + 4) & 63, sw = (rw + 4) & 63;
    const float* arow = x + (((size_t)(b * 64 + sh) * 64 + sw) * 256);

    int bf = tid >> 2;          // 0..63 (f offset in tile)
    int bk = (tid & 3) * 4;
    const float* brow = qkv_w + (size_t)(f0 + bf) * 256;

    float acc[4][4];
    #pragma unroll
    for (int i = 0; i < 4; ++i)
        #pragma unroll
        for (int j = 0; j < 4; ++j) acc[i][j] = 0.0f;

    for (int k0 = 0; k0 < 256; k0 += 16) {
        float4 av = *(const float4*)(arow + k0 + aj);
        float4 bv = *(const float4*)(brow + k0 + bk);
        As[ai][aj + 0] = av.x; As[ai][aj + 1] = av.y;
        As[ai][aj + 2] = av.z; As[ai][aj + 3] = av.w;
        Bs[bk + 0][bf] = bv.x; Bs[bk + 1][bf] = bv.y;
        Bs[bk + 2][bf] = bv.z; Bs[bk + 3][bf] = bv.w;
        __syncthreads();
        #pragma unroll
        for (int kk = 0; kk < 16; ++kk) {
            float a[4], bb[4];
            #pragma unroll
            for (int ii = 0; ii < 4; ++ii) a[ii] = As[ty4 + ii][kk];
            #pragma unroll
            for (int jj = 0; jj < 4; ++jj) bb[jj] = Bs[kk][tx4 + jj];
            #pragma unroll
            for (int ii = 0; ii < 4; ++ii)
                #pragma unroll
                for (int jj = 0; jj < 4; ++jj) acc[ii][jj] += a[ii] * bb[jj];
        }
        __syncthreads();
    }

    #pragma unroll
    for (int ii = 0; ii < 4; ++ii) {
        int mrow = m0 + ty4 + ii;
        int gw2 = mrow >> 6, l2 = mrow & 63;
        #pragma unroll
        for (int jj = 0; jj < 4; ++jj) {
            int f = f0 + tx4 + jj;
            float val = acc[ii][jj] + qkv_b[f];
            int s = f >> 8;
            int h = (f >> 5) & 7;
            int dd = f & 31;
            if (s == 0) val *= 0.17677669529663689f;  // 32^-0.5
            float* dst = (s == 0) ? qb : ((s == 1) ? kb : vb);
            dst[((size_t)(gw2 * 8 + h) * 64 + l2) * 32 + dd] = val;
        }
    }
}

// ---------------------------------------------------------------------------
// K2: per-window attention (all 8 heads). grid=512 windows, 256 threads.
// Writes attn_out [window][l][h*32+dd]  (= pre-proj features, row-major C=256)
// ---------------------------------------------------------------------------
__global__ __launch_bounds__(256) void attn_kernel(
    const float* __restrict__ q, const float* __restrict__ kmat,
    const float* __restrict__ v, const float* __restrict__ rel_bias,
    float* __restrict__ attn_out) {
    int n = blockIdx.x;           // global window 0..511
    int win = n & 63;
    int wy = win >> 3, wx = win & 7;
    int tid = threadIdx.x;

    __shared__ float qs[64][33], ks[64][33], vs[64][33];
    __shared__ float at[64][65];
    __shared__ int rgn[64];

    if (tid < 64) {
        int ly = tid >> 3, lx = tid & 7;
        int rh = wy * 8 + ly, rw = wx * 8 + lx;
        int bh = rh < 56 ? 0 : (rh < 60 ? 1 : 2);
        int bw = rw < 56 ? 0 : (rw < 60 ? 1 : 2);
        rgn[tid] = bh * 3 + bw;
    }

    int l = tid & 63, quad = tid >> 6;

    for (int h = 0; h < 8; ++h) {
        __syncthreads();  // protect previous iteration reads + rgn at h=0
        const float* qp = q    + (size_t)(n * 8 + h) * 2048;
        const float* kp = kmat + (size_t)(n * 8 + h) * 2048;
        const float* vp = v    + (size_t)(n * 8 + h) * 2048;
        for (int idx = tid; idx < 2048; idx += 256) {
            int l2 = idx >> 5, d2 = idx & 31;
            qs[l2][d2] = qp[idx];
            ks[l2][d2] = kp[idx];
            vs[l2][d2] = vp[idx];
        }
        __syncthreads();

        // scores: each thread does 16 entries of row l
        const float* rb = rel_bias + (size_t)(h * 64 + l) * 64;
        int rl = rgn[l];
        for (int mm = quad * 16; mm < quad * 16 + 16; ++mm) {
            float s = 0.0f;
            #pragma unroll
            for (int d2 = 0; d2 < 32; ++d2) s += qs[l][d2] * ks[mm][d2];
            s += rb[mm];
            if (rl != rgn[mm]) s -= 100.0f;
            at[l][mm] = s;
        }
        __syncthreads();

        // softmax per row (threads 0..63)
        if (tid < 64) {
            float mx = -1e30f;
            for (int mm = 0; mm < 64; ++mm) mx = fmaxf(mx, at[tid][mm]);
            float sum = 0.0f;
            for (int mm = 0; mm < 64; ++mm) {
                float e = expf(at[tid][mm] - mx);
                at[tid][mm] = e;
                sum += e;
            }
            float inv = 1.0f / sum;
            for (int mm = 0; mm < 64; ++mm) at[tid][mm] *= inv;
        }
        __syncthreads();

        // PV: thread -> (l, 8 dims starting at quad*8)
        int dd0 = quad * 8;
        float acc[8];
        #pragma unroll
        for (int j = 0; j < 8; ++j) acc[j] = 0.0f;
        for (int mm = 0; mm < 64; ++mm) {
            float a = at[l][mm];
            #pragma unroll
            for (int j = 0; j < 8; ++j) acc[j] += a * vs[mm][dd0 + j];
        }
        float* op = attn_out + ((size_t)(n * 64 + l) * 256) + h * 32 + dd0;
        #pragma unroll
        for (int j = 0; j < 8; ++j) op[j] = acc[j];
    }
}

// ---------------------------------------------------------------------------
// K3: proj GEMM. M=32768, N=256, K=256. A = attn_out (contiguous rows).
// Epilogue: +proj_b, un-window + un-roll, write feat (B,H,W,C).
// ---------------------------------------------------------------------------
__global__ __launch_bounds__(256) void proj_gemm_kernel(
    const float* __restrict__ attn_o, const float* __restrict__ proj_w,
    const float* __restrict__ proj_b, float* __restrict__ feat) {
    __shared__ float As[64][17];
    __shared__ float Bs[16][65];
    int tid = threadIdx.x;
    int tx = tid & 15, ty = tid >> 4;
    int tx4 = tx * 4, ty4 = ty * 4;
    int f0 = blockIdx.x * 64;
    int m0 = blockIdx.y * 64;

    int ai = tid >> 2;
    int aj = (tid & 3) * 4;
    const float* arow = attn_o + (size_t)(m0 + ai) * 256;
    int bf = tid >> 2;
    int bk = (tid & 3) * 4;
    const float* brow = proj_w + (size_t)(f0 + bf) * 256;

    float acc[4][4];
    #pragma unroll
    for (int i = 0; i < 4; ++i)
        #pragma unroll
        for (int j = 0; j < 4; ++j) acc[i][j] = 0.0f;

    for (int k0 = 0; k0 < 256; k0 += 16) {
        float4 av = *(const float4*)(arow + k0 + aj);
        float4 bv = *(const float4*)(brow + k0 + bk);
        As[ai][aj + 0] = av.x; As[ai][aj + 1] = av.y;
        As[ai][aj + 2] = av.z; As[ai][aj + 3] = av.w;
        Bs[bk + 0][bf] = bv.x; Bs[bk + 1][bf] = bv.y;
        Bs[bk + 2][bf] = bv.z; Bs[bk + 3][bf] = bv.w;
        __syncthreads();
        #pragma unroll
        for (int kk = 0; kk < 16; ++kk) {
            float a[4], bb[4];
            #pragma unroll
            for (int ii = 0; ii < 4; ++ii) a[ii] = As[ty4 + ii][kk];
            #pragma unroll
            for (int jj = 0; jj < 4; ++jj) bb[jj] = Bs[kk][tx4 + jj];
            #pragma unroll
            for (int ii = 0; ii < 4; ++ii)
                #pragma unroll
                for (int jj = 0; jj < 4; ++jj) acc[ii][jj] += a[ii] * bb[jj];
        }
        __syncthreads();
    }

    #pragma unroll
    for (int ii = 0; ii < 4; ++ii) {
        int mrow = m0 + ty4 + ii;
        int gw2 = mrow >> 6, l2 = mrow & 63;
        int b = gw2 >> 6, win = gw2 & 63;
        int rh = ((win >> 3) << 3) + (l2 >> 3);
        int rw = ((win & 7) << 3) + (l2 & 7);
        int p = (rh + 4) & 63;   // un-roll (+SS)
        int qq = (rw + 4) & 63;
        float* frow = feat + ((size_t)(b * 64 + p) * 64 + qq) * 256;
        #pragma unroll
        for (int jj = 0; jj < 4; ++jj) {
            int f = f0 + tx4 + jj;
            frow[f] = acc[ii][jj] + proj_b[f];
        }
    }
}

// ---------------------------------------------------------------------------
// K5: fused bilinear-sample + conv (stride (9,1)) + bias + ReLU.
// Block = 16 output pixels (one b,wd, hd0..hd0+15), 256 threads = 256 output ch.
// x-coordinate of sample is exactly integer (wx==0) -> 2-point interp in y.
// ---------------------------------------------------------------------------
__global__ __launch_bounds__(256) void sample_conv_kernel(
    const float* __restrict__ feat, const float* __restrict__ ymap,
    const float* __restrict__ wT, const float* __restrict__ dsc_b,
    float* __restrict__ out) {
    int blk = blockIdx.x;          // 0..2047
    int pix0 = blk * 16;
    int b   = pix0 >> 12;
    int wd  = (pix0 >> 6) & 63;
    int hd0 = pix0 & 63;
    int tid = threadIdx.x;

    __shared__ float sbuf[9][64][16];   // [k][i_local][pixel]
    __shared__ float wyv[9][16];
    __shared__ int   ry0[9][16], ry1[9][16], rxc[9][16];

    if (tid < 144) {
        int k = tid / 16, pi = tid % 16;
        int hd = hd0 + pi;
        float y = ymap[((size_t)(b * 576 + wd * 9 + k)) * 64 + hd];
        y = fminf(fmaxf(y, 0.0f), 63.0f);
        float y0f = floorf(y);
        wyv[k][pi] = y - y0f;
        int y0 = (int)y0f;
        ry0[k][pi] = y0;
        ry1[k][pi] = min(y0 + 1, 63);
        int xc = hd + k - 4;
        rxc[k][pi] = max(0, min(xc, 63));
    }

    float acc[16];
    #pragma unroll
    for (int p = 0; p < 16; ++p) acc[p] = 0.0f;

    for (int ic = 0; ic < 4; ++ic) {   // channel chunks of 64
        __syncthreads();               // coords ready / prev reads done
        for (int idx = tid; idx < 144; idx += 256) {
            int k = idx / 16, pi = idx % 16;
            int y0 = ry0[k][pi], y1 = ry1[k][pi], xc = rxc[k][pi];
            float wy = wyv[k][pi];
            float om = 1.0f - wy;
            const float4* r0 = (const float4*)(feat + (((size_t)(b * 64 + y0) * 64 + xc) * 256 + ic * 64));
            const float4* r1 = (const float4*)(feat + (((size_t)(b * 64 + y1) * 64 + xc) * 256 + ic * 64));
            #pragma unroll
            for (int j4 = 0; j4 < 16; ++j4) {
                float4 a = r0[j4];
                float4 c = r1[j4];
                sbuf[k][j4 * 4 + 0][pi] = a.x * om + c.x * wy;
                sbuf[k][j4 * 4 + 1][pi] = a.y * om + c.y * wy;
                sbuf[k][j4 * 4 + 2][pi] = a.z * om + c.z * wy;
                sbuf[k][j4 * 4 + 3][pi] = a.w * om + c.w * wy;
            }
        }
        __syncthreads();
        #pragma unroll 1
        for (int k = 0; k < 9; ++k) {
            for (int i = 0; i < 64; ++i) {
                float wv = wT[((size_t)(k * 256) + ic * 64 + i) * 256 + tid];
                const float4* sp = (const float4*)&sbuf[k][i][0];
                float4 s0 = sp[0], s1 = sp[1], s2 = sp[2], s3 = sp[3];
                acc[0]  += wv * s0.x; acc[1]  += wv * s0.y;
                acc[2]  += wv * s0.z; acc[3]  += wv * s0.w;
                acc[4]  += wv * s1.x; acc[5]  += wv * s1.y;
                acc[6]  += wv * s1.z; acc[7]  += wv * s1.w;
                acc[8]  += wv * s2.x; acc[9]  += wv * s2.y;
                acc[10] += wv * s2.z; acc[11] += wv * s2.w;
                acc[12] += wv * s3.x; acc[13] += wv * s3.y;
                acc[14] += wv * s3.z; acc[15] += wv * s3.w;
            }
        }
    }

    float bv = dsc_b[tid];
    float* orow = out + ((size_t)(b * 256 + tid) * 64 + wd) * 64 + hd0;
    #pragma unroll
    for (int p = 0; p < 16; ++p) {
        float v2 = acc[p] + bv;
        orow[p] = v2 > 0.0f ? v2 : 0.0f;
    }
}

// ---------------------------------------------------------------------------
extern "C" void kernel_launch(void* const* d_in, const int* in_sizes, int n_in,
                              void* d_out, int out_size, void* d_ws, size_t ws_size,
                              hipStream_t stream) {
    (void)in_sizes; (void)n_in; (void)out_size; (void)ws_size;
    const float* x        = (const float*)d_in[0];
    const float* qkv_w    = (const float*)d_in[1];
    const float* qkv_b    = (const float*)d_in[2];
    const float* proj_w   = (const float*)d_in[3];
    const float* proj_b   = (const float*)d_in[4];
    const float* rel_bias = (const float*)d_in[5];
    const float* offset   = (const float*)d_in[6];
    const float* dsc_w    = (const float*)d_in[7];
    const float* dsc_b    = (const float*)d_in[8];
    float* out = (float*)d_out;

    float* ws     = (float*)d_ws;
    float* qb     = ws;                     // 8.39M floats
    float* kb     = qb + NFLOAT_BUF;
    float* vb     = kb + NFLOAT_BUF;
    float* attn_o = vb + NFLOAT_BUF;
    float* feat   = attn_o + NFLOAT_BUF;
    float* ymap   = feat + NFLOAT_BUF;      // 294912 floats
    float* wT     = ymap + 294912;          // 589824 floats

    transpose_w_kernel<<<2304, 256, 0, stream>>>(dsc_w, wT);
    ymap_kernel<<<128, 256, 0, stream>>>(offset, ymap);
    qkv_gemm_kernel<<<dim3(12, 512), 256, 0, stream>>>(x, qkv_w, qkv_b, qb, kb, vb);
    attn_kernel<<<512, 256, 0, stream>>>(qb, kb, vb, rel_bias, attn_o);
    proj_gemm_kernel<<<dim3(4, 512), 256, 0, stream>>>(attn_o, proj_w, proj_b, feat);
    sample_conv_kernel<<<2048, 256, 0, stream>>>(feat, ymap, wT, dsc_b, out);
}

// Round 2
// 591.717 us; speedup vs baseline: 1.9260x; 1.9260x over previous
//
#include <hip/hip_runtime.h>
#include <math.h>

// Shapes: B=8, H=W=64, C=256, HEADS=8, d=32, WS=8, SS=4, K=9
// NTOK = 8*64*64 = 32768 tokens; 512 windows of 64 tokens.
// Conv = implicit GEMM: M=32768 px, N=256 out-ch, K=2304 (9 taps x 256 ch).

#define NFLOAT_BUF 8388608  // 32768*256

typedef float f32x4 __attribute__((ext_vector_type(4)));
typedef __bf16 bf16x8 __attribute__((ext_vector_type(8)));

__device__ inline unsigned pack2_bf16(float a, float b) {
    union { float f; unsigned u; } ua, ub;
    ua.f = a; ub.f = b;
    unsigned ra = (ua.u + 0x7FFFu + ((ua.u >> 16) & 1u)) >> 16;
    unsigned rb = (ub.u + 0x7FFFu + ((ub.u >> 16) & 1u)) & 0xFFFF0000u;
    return (ra & 0xFFFFu) | rb;
}

// ---------------------------------------------------------------------------
// K0: dsc_weight (O=256, I=256, K=9) -> wT2 bf16 [o][kk=k*256+i]  (K-major rows)
// ---------------------------------------------------------------------------
__global__ __launch_bounds__(256) void transpose_w_kernel(const float* __restrict__ w,
                                                          unsigned short* __restrict__ wT) {
    int t = blockIdx.x * 256 + threadIdx.x;   // < 589824
    int o = t / 2304;
    int kk = t - o * 2304;
    int k = kk >> 8, i = kk & 255;
    union { float f; unsigned u; } v;
    v.f = w[(o * 256 + i) * 9 + k];
    wT[t] = (unsigned short)((v.u + 0x7FFFu + ((v.u >> 16) & 1u)) >> 16);
}

// ---------------------------------------------------------------------------
// K4: snake coordinate map (y only; x is analytic integer) -> ymap[b][wd*9+k][hd]
// ---------------------------------------------------------------------------
__global__ __launch_bounds__(256) void ymap_kernel(const float* __restrict__ offset,
                                                   float* __restrict__ ymap) {
    int t = blockIdx.x * 256 + threadIdx.x;   // < 32768
    int hd = t & 63;
    int wd = (t >> 6) & 63;
    int b  = t >> 12;
    const float* op = offset + ((size_t)(b * 18) * 64 + wd) * 64 + hd;
    float yo[9];
    #pragma unroll
    for (int k = 0; k < 9; ++k) yo[k] = op[(size_t)k * 4096];
    float cum[9];
    cum[4] = 0.0f;
    float s = 0.0f;
    for (int j = 3; j >= 0; --j) { s += yo[j]; cum[j] = s; }
    s = 0.0f;
    for (int j = 5; j < 9; ++j) { s += yo[j]; cum[j] = s; }
    float wdf = (float)wd;
    float* yp = ymap + ((size_t)(b * 576 + wd * 9)) * 64 + hd;
    #pragma unroll
    for (int k = 0; k < 9; ++k) yp[(size_t)k * 64] = wdf + cum[k];
}

// ---------------------------------------------------------------------------
// K1: QKV GEMM (fp32). M=32768, N=768, K=256.
// ---------------------------------------------------------------------------
__global__ __launch_bounds__(256) void qkv_gemm_kernel(
    const float* __restrict__ x, const float* __restrict__ qkv_w,
    const float* __restrict__ qkv_b,
    float* __restrict__ qb, float* __restrict__ kb, float* __restrict__ vb) {
    __shared__ float As[64][17];
    __shared__ float Bs[16][65];
    int tid = threadIdx.x;
    int tx = tid & 15, ty = tid >> 4;
    int tx4 = tx * 4, ty4 = ty * 4;
    int f0 = blockIdx.x * 64;
    int m0 = blockIdx.y * 64;

    int ai = tid >> 2;
    int aj = (tid & 3) * 4;
    int m  = m0 + ai;
    int gw = m >> 6, l = m & 63;
    int b  = gw >> 6, win = gw & 63;
    int rh = ((win >> 3) << 3) + (l >> 3);
    int rw = ((win & 7) << 3) + (l & 7);
    int sh = (rh + 4) & 63, sw = (rw + 4) & 63;
    const float* arow = x + (((size_t)(b * 64 + sh) * 64 + sw) * 256);

    int bf = tid >> 2;
    int bk = (tid & 3) * 4;
    const float* brow = qkv_w + (size_t)(f0 + bf) * 256;

    float acc[4][4];
    #pragma unroll
    for (int i = 0; i < 4; ++i)
        #pragma unroll
        for (int j = 0; j < 4; ++j) acc[i][j] = 0.0f;

    for (int k0 = 0; k0 < 256; k0 += 16) {
        float4 av = *(const float4*)(arow + k0 + aj);
        float4 bv = *(const float4*)(brow + k0 + bk);
        As[ai][aj + 0] = av.x; As[ai][aj + 1] = av.y;
        As[ai][aj + 2] = av.z; As[ai][aj + 3] = av.w;
        Bs[bk + 0][bf] = bv.x; Bs[bk + 1][bf] = bv.y;
        Bs[bk + 2][bf] = bv.z; Bs[bk + 3][bf] = bv.w;
        __syncthreads();
        #pragma unroll
        for (int kk = 0; kk < 16; ++kk) {
            float a[4], bb[4];
            #pragma unroll
            for (int ii = 0; ii < 4; ++ii) a[ii] = As[ty4 + ii][kk];
            #pragma unroll
            for (int jj = 0; jj < 4; ++jj) bb[jj] = Bs[kk][tx4 + jj];
            #pragma unroll
            for (int ii = 0; ii < 4; ++ii)
                #pragma unroll
                for (int jj = 0; jj < 4; ++jj) acc[ii][jj] += a[ii] * bb[jj];
        }
        __syncthreads();
    }

    #pragma unroll
    for (int ii = 0; ii < 4; ++ii) {
        int mrow = m0 + ty4 + ii;
        int gw2 = mrow >> 6, l2 = mrow & 63;
        #pragma unroll
        for (int jj = 0; jj < 4; ++jj) {
            int f = f0 + tx4 + jj;
            float val = acc[ii][jj] + qkv_b[f];
            int s = f >> 8;
            int h = (f >> 5) & 7;
            int dd = f & 31;
            if (s == 0) val *= 0.17677669529663689f;  // 32^-0.5
            float* dst = (s == 0) ? qb : ((s == 1) ? kb : vb);
            dst[((size_t)(gw2 * 8 + h) * 64 + l2) * 32 + dd] = val;
        }
    }
}

// ---------------------------------------------------------------------------
// K2: per-window attention (fp32), unchanged.
// ---------------------------------------------------------------------------
__global__ __launch_bounds__(256) void attn_kernel(
    const float* __restrict__ q, const float* __restrict__ kmat,
    const float* __restrict__ v, const float* __restrict__ rel_bias,
    float* __restrict__ attn_out) {
    int n = blockIdx.x;
    int win = n & 63;
    int wy = win >> 3, wx = win & 7;
    int tid = threadIdx.x;

    __shared__ float qs[64][33], ks[64][33], vs[64][33];
    __shared__ float at[64][65];
    __shared__ int rgn[64];

    if (tid < 64) {
        int ly = tid >> 3, lx = tid & 7;
        int rh = wy * 8 + ly, rw = wx * 8 + lx;
        int bh = rh < 56 ? 0 : (rh < 60 ? 1 : 2);
        int bw = rw < 56 ? 0 : (rw < 60 ? 1 : 2);
        rgn[tid] = bh * 3 + bw;
    }

    int l = tid & 63, quad = tid >> 6;

    for (int h = 0; h < 8; ++h) {
        __syncthreads();
        const float* qp = q    + (size_t)(n * 8 + h) * 2048;
        const float* kp = kmat + (size_t)(n * 8 + h) * 2048;
        const float* vp = v    + (size_t)(n * 8 + h) * 2048;
        for (int idx = tid; idx < 2048; idx += 256) {
            int l2 = idx >> 5, d2 = idx & 31;
            qs[l2][d2] = qp[idx];
            ks[l2][d2] = kp[idx];
            vs[l2][d2] = vp[idx];
        }
        __syncthreads();

        const float* rb = rel_bias + (size_t)(h * 64 + l) * 64;
        int rl = rgn[l];
        for (int mm = quad * 16; mm < quad * 16 + 16; ++mm) {
            float s = 0.0f;
            #pragma unroll
            for (int d2 = 0; d2 < 32; ++d2) s += qs[l][d2] * ks[mm][d2];
            s += rb[mm];
            if (rl != rgn[mm]) s -= 100.0f;
            at[l][mm] = s;
        }
        __syncthreads();

        if (tid < 64) {
            float mx = -1e30f;
            for (int mm = 0; mm < 64; ++mm) mx = fmaxf(mx, at[tid][mm]);
            float sum = 0.0f;
            for (int mm = 0; mm < 64; ++mm) {
                float e = expf(at[tid][mm] - mx);
                at[tid][mm] = e;
                sum += e;
            }
            float inv = 1.0f / sum;
            for (int mm = 0; mm < 64; ++mm) at[tid][mm] *= inv;
        }
        __syncthreads();

        int dd0 = quad * 8;
        float acc[8];
        #pragma unroll
        for (int j = 0; j < 8; ++j) acc[j] = 0.0f;
        for (int mm = 0; mm < 64; ++mm) {
            float a = at[l][mm];
            #pragma unroll
            for (int j = 0; j < 8; ++j) acc[j] += a * vs[mm][dd0 + j];
        }
        float* op = attn_out + ((size_t)(n * 64 + l) * 256) + h * 32 + dd0;
        #pragma unroll
        for (int j = 0; j < 8; ++j) op[j] = acc[j];
    }
}

// ---------------------------------------------------------------------------
// K3: proj GEMM (fp32 compute). Epilogue now writes feat as bf16 (un-window+un-roll).
// ---------------------------------------------------------------------------
__global__ __launch_bounds__(256) void proj_gemm_kernel(
    const float* __restrict__ attn_o, const float* __restrict__ proj_w,
    const float* __restrict__ proj_b, unsigned short* __restrict__ featb) {
    __shared__ float As[64][17];
    __shared__ float Bs[16][65];
    int tid = threadIdx.x;
    int tx = tid & 15, ty = tid >> 4;
    int tx4 = tx * 4, ty4 = ty * 4;
    int f0 = blockIdx.x * 64;
    int m0 = blockIdx.y * 64;

    int ai = tid >> 2;
    int aj = (tid & 3) * 4;
    const float* arow = attn_o + (size_t)(m0 + ai) * 256;
    int bf = tid >> 2;
    int bk = (tid & 3) * 4;
    const float* brow = proj_w + (size_t)(f0 + bf) * 256;

    float acc[4][4];
    #pragma unroll
    for (int i = 0; i < 4; ++i)
        #pragma unroll
        for (int j = 0; j < 4; ++j) acc[i][j] = 0.0f;

    for (int k0 = 0; k0 < 256; k0 += 16) {
        float4 av = *(const float4*)(arow + k0 + aj);
        float4 bv = *(const float4*)(brow + k0 + bk);
        As[ai][aj + 0] = av.x; As[ai][aj + 1] = av.y;
        As[ai][aj + 2] = av.z; As[ai][aj + 3] = av.w;
        Bs[bk + 0][bf] = bv.x; Bs[bk + 1][bf] = bv.y;
        Bs[bk + 2][bf] = bv.z; Bs[bk + 3][bf] = bv.w;
        __syncthreads();
        #pragma unroll
        for (int kk = 0; kk < 16; ++kk) {
            float a[4], bb[4];
            #pragma unroll
            for (int ii = 0; ii < 4; ++ii) a[ii] = As[ty4 + ii][kk];
            #pragma unroll
            for (int jj = 0; jj < 4; ++jj) bb[jj] = Bs[kk][tx4 + jj];
            #pragma unroll
            for (int ii = 0; ii < 4; ++ii)
                #pragma unroll
                for (int jj = 0; jj < 4; ++jj) acc[ii][jj] += a[ii] * bb[jj];
        }
        __syncthreads();
    }

    #pragma unroll
    for (int ii = 0; ii < 4; ++ii) {
        int mrow = m0 + ty4 + ii;
        int gw2 = mrow >> 6, l2 = mrow & 63;
        int b = gw2 >> 6, win = gw2 & 63;
        int rh = ((win >> 3) << 3) + (l2 >> 3);
        int rw = ((win & 7) << 3) + (l2 & 7);
        int p = (rh + 4) & 63;
        int qq = (rw + 4) & 63;
        unsigned short* frow = featb + (((size_t)(b * 64 + p) * 64 + qq) * 256);
        int f = f0 + tx4;
        float v0 = acc[ii][0] + proj_b[f + 0];
        float v1 = acc[ii][1] + proj_b[f + 1];
        float v2 = acc[ii][2] + proj_b[f + 2];
        float v3 = acc[ii][3] + proj_b[f + 3];
        uint2 pk;
        pk.x = pack2_bf16(v0, v1);
        pk.y = pack2_bf16(v2, v3);
        *(uint2*)(frow + f) = pk;
    }
}

// ---------------------------------------------------------------------------
// K5: fused bilinear-sample + conv via bf16 MFMA implicit GEMM.
// Block = 64 pixels (one b,wd; hd=0..63) x all 256 out-ch. 4 waves, each 64px x 64oc.
// K=2304 in 36 chunks of 64 (ksnake = c>>2, channels (c&3)*64..+63).
// A tile: interpolated samples, bf16, [px][64] with 16B-slot XOR swizzle.
// B tile: wT2[o][kk] staged via global_load_lds (inverse-swizzled source).
// ---------------------------------------------------------------------------
__global__ __launch_bounds__(256) void sample_conv_mfma_kernel(
    const unsigned short* __restrict__ featb, const float* __restrict__ ymap,
    const unsigned short* __restrict__ wT2, const float* __restrict__ dsc_b,
    float* __restrict__ out) {

    __shared__ __align__(16) char Asb[8192];    // 64 px * 128B
    __shared__ __align__(16) char Bsb[32768];   // 256 o * 128B
    __shared__ unsigned row0[9][64];
    __shared__ unsigned row1[9][64];
    __shared__ float    wyv[9][64];

    int blk = blockIdx.x;              // 0..511 = b*64 + wd
    int b = blk >> 6, wd = blk & 63;
    int tid = threadIdx.x;
    int lane = tid & 63, w = tid >> 6;

    // --- per-block sample coordinates: 9 taps x 64 pixels ---
    for (int idx = tid; idx < 576; idx += 256) {
        int k = idx >> 6, hd = idx & 63;
        float y = ymap[((size_t)(b * 576 + wd * 9 + k)) * 64 + hd];
        y = fminf(fmaxf(y, 0.0f), 63.0f);
        float y0f = floorf(y);
        int y0 = (int)y0f;
        int y1 = min(y0 + 1, 63);
        int xc = min(max(hd + k - 4, 0), 63);
        row0[k][hd] = (unsigned)(((b * 64 + y0) * 64 + xc) * 512);  // byte offset
        row1[k][hd] = (unsigned)(((b * 64 + y1) * 64 + xc) * 512);
        wyv[k][hd] = y - y0f;
    }

    f32x4 acc[4][4];
    #pragma unroll
    for (int m = 0; m < 4; ++m)
        #pragma unroll
        for (int n = 0; n < 4; ++n) {
            f32x4 z = {0.0f, 0.0f, 0.0f, 0.0f};
            acc[m][n] = z;
        }

    const char* featc = (const char*)featb;
    const char* wc    = (const char*)wT2;

    int pxA0 = tid >> 3;   // A-stage: r=0 pixel
    int sA   = tid & 7;    // A-stage: 16B slot (8 channels)

    // fragment address constants (swizzled): u = (slot ^ (row&7))*16, row&7 == lane&7
    int rA = (lane & 15) * 128;
    int u0 = (((lane >> 4)    ) ^ (lane & 7)) << 4;   // kb=0 slots 0..3
    int u1 = ((4 + (lane >> 4)) ^ (lane & 7)) << 4;   // kb=1 slots 4..7

    __syncthreads();

    for (int c = 0; c < 36; ++c) {
        // --- stage B: 256 rows x 128B, linear LDS dest, inverse-swizzled source ---
        #pragma unroll
        for (int r = 0; r < 8; ++r) {
            int pos = r * 256 + tid;          // 16B slot index in Bsb
            int n = pos >> 3, uu = pos & 7;
            int s = uu ^ (n & 7);
            const char* src = wc + n * 4608 + c * 128 + s * 16;
            __builtin_amdgcn_global_load_lds(
                (const __attribute__((address_space(1))) unsigned int*)src,
                (__attribute__((address_space(3))) unsigned int*)(Bsb + pos * 16),
                16, 0, 0);
        }
        // --- stage A: gather + lerp + pack, swizzled ds_write ---
        int ks  = c >> 2;
        int cib = (c & 3) * 128;
        #pragma unroll
        for (int r = 0; r < 2; ++r) {
            int px = pxA0 + r * 32;
            unsigned b0 = row0[ks][px] + cib + sA * 16;
            unsigned b1 = row1[ks][px] + cib + sA * 16;
            float wy = wyv[ks][px];
            float om = 1.0f - wy;
            uint4 v0 = *(const uint4*)(featc + b0);
            uint4 v1 = *(const uint4*)(featc + b1);
            const unsigned* q0 = (const unsigned*)&v0;
            const unsigned* q1 = (const unsigned*)&v1;
            uint4 o4;
            unsigned* qo = (unsigned*)&o4;
            #pragma unroll
            for (int j = 0; j < 4; ++j) {
                union { unsigned u; float f; } alo, ahi, blo, bhi;
                alo.u = q0[j] << 16; ahi.u = q0[j] & 0xFFFF0000u;
                blo.u = q1[j] << 16; bhi.u = q1[j] & 0xFFFF0000u;
                float rlo = alo.f * om + blo.f * wy;
                float rhi = ahi.f * om + bhi.f * wy;
                qo[j] = pack2_bf16(rlo, rhi);
            }
            *(uint4*)(Asb + px * 128 + ((sA ^ (px & 7)) << 4)) = o4;
        }
        __syncthreads();

        // --- fragments + MFMA: wave w owns out-ch [w*64, w*64+64) ---
        bf16x8 av[4][2], bv[4][2];
        #pragma unroll
        for (int m = 0; m < 4; ++m) {
            av[m][0] = *(const bf16x8*)(Asb + m * 2048 + rA + u0);
            av[m][1] = *(const bf16x8*)(Asb + m * 2048 + rA + u1);
        }
        #pragma unroll
        for (int n = 0; n < 4; ++n) {
            bv[n][0] = *(const bf16x8*)(Bsb + w * 8192 + n * 2048 + rA + u0);
            bv[n][1] = *(const bf16x8*)(Bsb + w * 8192 + n * 2048 + rA + u1);
        }
        #pragma unroll
        for (int m = 0; m < 4; ++m)
            #pragma unroll
            for (int n = 0; n < 4; ++n) {
                acc[m][n] = __builtin_amdgcn_mfma_f32_16x16x32_bf16(av[m][0], bv[n][0], acc[m][n], 0, 0, 0);
                acc[m][n] = __builtin_amdgcn_mfma_f32_16x16x32_bf16(av[m][1], bv[n][1], acc[m][n], 0, 0, 0);
            }
        __syncthreads();
    }

    // --- epilogue: C frag (col=lane&15 -> o, row=(lane>>4)*4+r -> px), +bias, ReLU ---
    #pragma unroll
    for (int n = 0; n < 4; ++n) {
        int o = w * 64 + n * 16 + (lane & 15);
        float bvs = dsc_b[o];
        float* orow = out + ((size_t)(b * 256 + o) * 64 + wd) * 64;
        #pragma unroll
        for (int m = 0; m < 4; ++m) {
            int px = m * 16 + (lane >> 4) * 4;
            float4 res;
            res.x = fmaxf(acc[m][n][0] + bvs, 0.0f);
            res.y = fmaxf(acc[m][n][1] + bvs, 0.0f);
            res.z = fmaxf(acc[m][n][2] + bvs, 0.0f);
            res.w = fmaxf(acc[m][n][3] + bvs, 0.0f);
            *(float4*)(orow + px) = res;
        }
    }
}

// ---------------------------------------------------------------------------
extern "C" void kernel_launch(void* const* d_in, const int* in_sizes, int n_in,
                              void* d_out, int out_size, void* d_ws, size_t ws_size,
                              hipStream_t stream) {
    (void)in_sizes; (void)n_in; (void)out_size; (void)ws_size;
    const float* x        = (const float*)d_in[0];
    const float* qkv_w    = (const float*)d_in[1];
    const float* qkv_b    = (const float*)d_in[2];
    const float* proj_w   = (const float*)d_in[3];
    const float* proj_b   = (const float*)d_in[4];
    const float* rel_bias = (const float*)d_in[5];
    const float* offset   = (const float*)d_in[6];
    const float* dsc_w    = (const float*)d_in[7];
    const float* dsc_b    = (const float*)d_in[8];
    float* out = (float*)d_out;

    float* ws     = (float*)d_ws;
    float* qb     = ws;
    float* kb     = qb + NFLOAT_BUF;
    float* vb     = kb + NFLOAT_BUF;
    float* attn_o = vb + NFLOAT_BUF;
    unsigned short* featb = (unsigned short*)(attn_o + NFLOAT_BUF);  // bf16 feat
    float* ymap   = (float*)(featb + NFLOAT_BUF);                    // 294912 floats
    unsigned short* wT2 = (unsigned short*)(ymap + 294912);          // 589824 bf16

    transpose_w_kernel<<<2304, 256, 0, stream>>>(dsc_w, wT2);
    ymap_kernel<<<128, 256, 0, stream>>>(offset, ymap);
    qkv_gemm_kernel<<<dim3(12, 512), 256, 0, stream>>>(x, qkv_w, qkv_b, qb, kb, vb);
    attn_kernel<<<512, 256, 0, stream>>>(qb, kb, vb, rel_bias, attn_o);
    proj_gemm_kernel<<<dim3(4, 512), 256, 0, stream>>>(attn_o, proj_w, proj_b, featb);
    sample_conv_mfma_kernel<<<512, 256, 0, stream>>>(featb, ymap, wT2, dsc_b, out);
}

// Round 3
// 334.942 us; speedup vs baseline: 3.4025x; 1.7666x over previous
//
#include <hip/hip_runtime.h>
#include <math.h>

// Shapes: B=8, H=W=64, C=256, HEADS=8, d=32, WS=8, SS=4, K=9
// NTOK = 32768 tokens; 512 windows of 64 tokens.
// Conv = implicit GEMM: M=32768 px, N=256 oc, K=2304.
// QKV  = GEMM M=32768, N=768, K=256 (bf16 MFMA).
// Proj = GEMM M=32768, N=256, K=256 (bf16 MFMA).

#define NFLOAT_BUF 8388608  // 32768*256

typedef float f32x4 __attribute__((ext_vector_type(4)));
typedef __bf16 bf16x8 __attribute__((ext_vector_type(8)));

__device__ inline unsigned pack2_bf16(float a, float b) {
    union { float f; unsigned u; } ua, ub;
    ua.f = a; ub.f = b;
    unsigned ra = (ua.u + 0x7FFFu + ((ua.u >> 16) & 1u)) >> 16;
    unsigned rb = (ub.u + 0x7FFFu + ((ub.u >> 16) & 1u)) & 0xFFFF0000u;
    return (ra & 0xFFFFu) | rb;
}
__device__ inline unsigned short pack1_bf16(float a) {
    union { float f; unsigned u; } v;
    v.f = a;
    return (unsigned short)((v.u + 0x7FFFu + ((v.u >> 16) & 1u)) >> 16);
}

// ---------------------------------------------------------------------------
// K-1: fp32 -> bf16 bulk convert (8 elems/thread)
// ---------------------------------------------------------------------------
__global__ __launch_bounds__(256) void cvt_bf16_kernel(const float* __restrict__ src,
                                                       unsigned short* __restrict__ dst,
                                                       int n8) {
    int t = blockIdx.x * 256 + threadIdx.x;
    if (t >= n8) return;
    const float4* s = (const float4*)(src + (size_t)t * 8);
    float4 a = s[0], b = s[1];
    uint4 o;
    o.x = pack2_bf16(a.x, a.y); o.y = pack2_bf16(a.z, a.w);
    o.z = pack2_bf16(b.x, b.y); o.w = pack2_bf16(b.z, b.w);
    *(uint4*)(dst + (size_t)t * 8) = o;
}

// ---------------------------------------------------------------------------
// K0: dsc_weight (O=256, I=256, K=9) -> wT2 bf16 [o][kk=k*256+i]
// ---------------------------------------------------------------------------
__global__ __launch_bounds__(256) void transpose_w_kernel(const float* __restrict__ w,
                                                          unsigned short* __restrict__ wT) {
    int t = blockIdx.x * 256 + threadIdx.x;   // < 589824
    int o = t / 2304;
    int kk = t - o * 2304;
    int k = kk >> 8, i = kk & 255;
    wT[t] = pack1_bf16(w[(o * 256 + i) * 9 + k]);
}

// ---------------------------------------------------------------------------
// K4: snake coordinate map -> ymap[b][wd*9+k][hd]
// ---------------------------------------------------------------------------
__global__ __launch_bounds__(256) void ymap_kernel(const float* __restrict__ offset,
                                                   float* __restrict__ ymap) {
    int t = blockIdx.x * 256 + threadIdx.x;   // < 32768
    int hd = t & 63;
    int wd = (t >> 6) & 63;
    int b  = t >> 12;
    const float* op = offset + ((size_t)(b * 18) * 64 + wd) * 64 + hd;
    float yo[9];
    #pragma unroll
    for (int k = 0; k < 9; ++k) yo[k] = op[(size_t)k * 4096];
    float cum[9];
    cum[4] = 0.0f;
    float s = 0.0f;
    for (int j = 3; j >= 0; --j) { s += yo[j]; cum[j] = s; }
    s = 0.0f;
    for (int j = 5; j < 9; ++j) { s += yo[j]; cum[j] = s; }
    float wdf = (float)wd;
    float* yp = ymap + ((size_t)(b * 576 + wd * 9)) * 64 + hd;
    #pragma unroll
    for (int k = 0; k < 9; ++k) yp[(size_t)k * 64] = wdf + cum[k];
}

// ---------------------------------------------------------------------------
// K1: QKV GEMM via bf16 MFMA. Block = 64 M-rows x 256 N. grid (3, 512).
// A rows gathered from xb via roll+window map; B = wb rows (qkv_w bf16).
// Epilogue: +bias, q-scale, scatter fp32 to [win][head][l][d].
// ---------------------------------------------------------------------------
__global__ __launch_bounds__(256) void qkv_mfma_kernel(
    const unsigned short* __restrict__ xb, const unsigned short* __restrict__ wb,
    const float* __restrict__ qkv_b,
    float* __restrict__ qb, float* __restrict__ kb, float* __restrict__ vb) {

    __shared__ __align__(16) char Asb[8192];    // 64 rows * 128B
    __shared__ __align__(16) char Bsb[32768];   // 256 rows * 128B
    __shared__ unsigned rowoff[64];

    int nb = blockIdx.x;          // 0..2  (N block of 256)
    int m0 = blockIdx.y * 64;
    int tid = threadIdx.x;
    int lane = tid & 63, w = tid >> 6;
    int gw = m0 >> 6;             // global window (uniform per block)

    if (tid < 64) {
        int l = tid;
        int b = gw >> 6, win = gw & 63;
        int rh = ((win >> 3) << 3) + (l >> 3);
        int rw = ((win & 7) << 3) + (l & 7);
        int sh = (rh + 4) & 63, sw = (rw + 4) & 63;
        rowoff[l] = (unsigned)(((b * 64 + sh) * 64 + sw) * 512);  // byte offset
    }

    f32x4 acc[4][4];
    #pragma unroll
    for (int m = 0; m < 4; ++m)
        #pragma unroll
        for (int n = 0; n < 4; ++n) {
            f32x4 z = {0.0f, 0.0f, 0.0f, 0.0f};
            acc[m][n] = z;
        }

    const char* xc = (const char*)xb;
    const char* wc = (const char*)wb;
    int rA = (lane & 15) * 128;
    int u0 = (((lane >> 4)    ) ^ (lane & 7)) << 4;
    int u1 = ((4 + (lane >> 4)) ^ (lane & 7)) << 4;

    __syncthreads();

    for (int c = 0; c < 4; ++c) {   // K chunks of 64
        // stage A: 64 rows x 8 slots, linear dest, inverse-swizzled source
        #pragma unroll
        for (int r = 0; r < 2; ++r) {
            int pos = r * 256 + tid;
            int row = pos >> 3, u = pos & 7;
            const char* src = xc + rowoff[row] + c * 128 + ((u ^ (row & 7)) << 4);
            __builtin_amdgcn_global_load_lds(
                (const __attribute__((address_space(1))) unsigned int*)src,
                (__attribute__((address_space(3))) unsigned int*)(Asb + pos * 16),
                16, 0, 0);
        }
        // stage B: 256 rows x 8 slots
        #pragma unroll
        for (int r = 0; r < 8; ++r) {
            int pos = r * 256 + tid;
            int n = pos >> 3, u = pos & 7;
            const char* src = wc + (size_t)(nb * 256 + n) * 512 + c * 128 + ((u ^ (n & 7)) << 4);
            __builtin_amdgcn_global_load_lds(
                (const __attribute__((address_space(1))) unsigned int*)src,
                (__attribute__((address_space(3))) unsigned int*)(Bsb + pos * 16),
                16, 0, 0);
        }
        __syncthreads();

        bf16x8 av[4][2], bv[4][2];
        #pragma unroll
        for (int m = 0; m < 4; ++m) {
            av[m][0] = *(const bf16x8*)(Asb + m * 2048 + rA + u0);
            av[m][1] = *(const bf16x8*)(Asb + m * 2048 + rA + u1);
        }
        #pragma unroll
        for (int n = 0; n < 4; ++n) {
            bv[n][0] = *(const bf16x8*)(Bsb + w * 8192 + n * 2048 + rA + u0);
            bv[n][1] = *(const bf16x8*)(Bsb + w * 8192 + n * 2048 + rA + u1);
        }
        #pragma unroll
        for (int m = 0; m < 4; ++m)
            #pragma unroll
            for (int n = 0; n < 4; ++n) {
                acc[m][n] = __builtin_amdgcn_mfma_f32_16x16x32_bf16(av[m][0], bv[n][0], acc[m][n], 0, 0, 0);
                acc[m][n] = __builtin_amdgcn_mfma_f32_16x16x32_bf16(av[m][1], bv[n][1], acc[m][n], 0, 0, 0);
            }
        __syncthreads();
    }

    // epilogue: C frag col = out feature, row = token l. s = nb (uniform).
    float scale = (nb == 0) ? 0.17677669529663689f : 1.0f;
    float* dstb = (nb == 0) ? qb : ((nb == 1) ? kb : vb);
    #pragma unroll
    for (int nf = 0; nf < 4; ++nf) {
        int o = w * 64 + nf * 16 + (lane & 15);   // 0..255 within the 256-group
        float bias = qkv_b[nb * 256 + o];
        int h = o >> 5, dd = o & 31;
        float* base = dstb + ((size_t)(gw * 8 + h) * 64) * 32 + dd;
        #pragma unroll
        for (int mf = 0; mf < 4; ++mf) {
            int px0 = mf * 16 + (lane >> 4) * 4;
            #pragma unroll
            for (int j = 0; j < 4; ++j) {
                float val = (acc[mf][nf][j] + bias) * scale;
                base[(size_t)(px0 + j) * 32] = val;
            }
        }
    }
}

// ---------------------------------------------------------------------------
// K2: per-window attention (fp32). Epilogue now writes attn_ob as bf16.
// ---------------------------------------------------------------------------
__global__ __launch_bounds__(256) void attn_kernel(
    const float* __restrict__ q, const float* __restrict__ kmat,
    const float* __restrict__ v, const float* __restrict__ rel_bias,
    unsigned short* __restrict__ attn_ob) {
    int n = blockIdx.x;
    int win = n & 63;
    int wy = win >> 3, wx = win & 7;
    int tid = threadIdx.x;

    __shared__ float qs[64][33], ks[64][33], vs[64][33];
    __shared__ float at[64][65];
    __shared__ int rgn[64];

    if (tid < 64) {
        int ly = tid >> 3, lx = tid & 7;
        int rh = wy * 8 + ly, rw = wx * 8 + lx;
        int bh = rh < 56 ? 0 : (rh < 60 ? 1 : 2);
        int bw = rw < 56 ? 0 : (rw < 60 ? 1 : 2);
        rgn[tid] = bh * 3 + bw;
    }

    int l = tid & 63, quad = tid >> 6;

    for (int h = 0; h < 8; ++h) {
        __syncthreads();
        const float* qp = q    + (size_t)(n * 8 + h) * 2048;
        const float* kp = kmat + (size_t)(n * 8 + h) * 2048;
        const float* vp = v    + (size_t)(n * 8 + h) * 2048;
        for (int idx = tid; idx < 2048; idx += 256) {
            int l2 = idx >> 5, d2 = idx & 31;
            qs[l2][d2] = qp[idx];
            ks[l2][d2] = kp[idx];
            vs[l2][d2] = vp[idx];
        }
        __syncthreads();

        const float* rb = rel_bias + (size_t)(h * 64 + l) * 64;
        int rl = rgn[l];
        for (int mm = quad * 16; mm < quad * 16 + 16; ++mm) {
            float s = 0.0f;
            #pragma unroll
            for (int d2 = 0; d2 < 32; ++d2) s += qs[l][d2] * ks[mm][d2];
            s += rb[mm];
            if (rl != rgn[mm]) s -= 100.0f;
            at[l][mm] = s;
        }
        __syncthreads();

        if (tid < 64) {
            float mx = -1e30f;
            for (int mm = 0; mm < 64; ++mm) mx = fmaxf(mx, at[tid][mm]);
            float sum = 0.0f;
            for (int mm = 0; mm < 64; ++mm) {
                float e = expf(at[tid][mm] - mx);
                at[tid][mm] = e;
                sum += e;
            }
            float inv = 1.0f / sum;
            for (int mm = 0; mm < 64; ++mm) at[tid][mm] *= inv;
        }
        __syncthreads();

        int dd0 = quad * 8;
        float acc[8];
        #pragma unroll
        for (int j = 0; j < 8; ++j) acc[j] = 0.0f;
        for (int mm = 0; mm < 64; ++mm) {
            float a = at[l][mm];
            #pragma unroll
            for (int j = 0; j < 8; ++j) acc[j] += a * vs[mm][dd0 + j];
        }
        unsigned short* op = attn_ob + ((size_t)(n * 64 + l) * 256) + h * 32 + dd0;
        uint4 pk;
        pk.x = pack2_bf16(acc[0], acc[1]);
        pk.y = pack2_bf16(acc[2], acc[3]);
        pk.z = pack2_bf16(acc[4], acc[5]);
        pk.w = pack2_bf16(acc[6], acc[7]);
        *(uint4*)op = pk;
    }
}

// ---------------------------------------------------------------------------
// K3: proj GEMM via bf16 MFMA. Block = 64 M x 256 N. grid 512.
// A = attn_ob rows (contiguous). Epilogue: +bias, un-window+un-roll, bf16 feat.
// ---------------------------------------------------------------------------
__global__ __launch_bounds__(256) void proj_mfma_kernel(
    const unsigned short* __restrict__ attn_ob, const unsigned short* __restrict__ pwb,
    const float* __restrict__ proj_b, unsigned short* __restrict__ featb) {

    __shared__ __align__(16) char Asb[8192];
    __shared__ __align__(16) char Bsb[32768];

    int m0 = blockIdx.x * 64;
    int tid = threadIdx.x;
    int lane = tid & 63, w = tid >> 6;
    int gw = m0 >> 6;
    int bidx = gw >> 6, win = gw & 63;

    f32x4 acc[4][4];
    #pragma unroll
    for (int m = 0; m < 4; ++m)
        #pragma unroll
        for (int n = 0; n < 4; ++n) {
            f32x4 z = {0.0f, 0.0f, 0.0f, 0.0f};
            acc[m][n] = z;
        }

    const char* ac = (const char*)attn_ob;
    const char* wc = (const char*)pwb;
    int rA = (lane & 15) * 128;
    int u0 = (((lane >> 4)    ) ^ (lane & 7)) << 4;
    int u1 = ((4 + (lane >> 4)) ^ (lane & 7)) << 4;

    for (int c = 0; c < 4; ++c) {
        #pragma unroll
        for (int r = 0; r < 2; ++r) {
            int pos = r * 256 + tid;
            int row = pos >> 3, u = pos & 7;
            const char* src = ac + (size_t)(m0 + row) * 512 + c * 128 + ((u ^ (row & 7)) << 4);
            __builtin_amdgcn_global_load_lds(
                (const __attribute__((address_space(1))) unsigned int*)src,
                (__attribute__((address_space(3))) unsigned int*)(Asb + pos * 16),
                16, 0, 0);
        }
        #pragma unroll
        for (int r = 0; r < 8; ++r) {
            int pos = r * 256 + tid;
            int n = pos >> 3, u = pos & 7;
            const char* src = wc + (size_t)n * 512 + c * 128 + ((u ^ (n & 7)) << 4);
            __builtin_amdgcn_global_load_lds(
                (const __attribute__((address_space(1))) unsigned int*)src,
                (__attribute__((address_space(3))) unsigned int*)(Bsb + pos * 16),
                16, 0, 0);
        }
        __syncthreads();

        bf16x8 av[4][2], bv[4][2];
        #pragma unroll
        for (int m = 0; m < 4; ++m) {
            av[m][0] = *(const bf16x8*)(Asb + m * 2048 + rA + u0);
            av[m][1] = *(const bf16x8*)(Asb + m * 2048 + rA + u1);
        }
        #pragma unroll
        for (int n = 0; n < 4; ++n) {
            bv[n][0] = *(const bf16x8*)(Bsb + w * 8192 + n * 2048 + rA + u0);
            bv[n][1] = *(const bf16x8*)(Bsb + w * 8192 + n * 2048 + rA + u1);
        }
        #pragma unroll
        for (int m = 0; m < 4; ++m)
            #pragma unroll
            for (int n = 0; n < 4; ++n) {
                acc[m][n] = __builtin_amdgcn_mfma_f32_16x16x32_bf16(av[m][0], bv[n][0], acc[m][n], 0, 0, 0);
                acc[m][n] = __builtin_amdgcn_mfma_f32_16x16x32_bf16(av[m][1], bv[n][1], acc[m][n], 0, 0, 0);
            }
        __syncthreads();
    }

    #pragma unroll
    for (int nf = 0; nf < 4; ++nf) {
        int f = w * 64 + nf * 16 + (lane & 15);
        float bias = proj_b[f];
        #pragma unroll
        for (int mf = 0; mf < 4; ++mf) {
            #pragma unroll
            for (int j = 0; j < 4; ++j) {
                int px = mf * 16 + (lane >> 4) * 4 + j;
                int rh = ((win >> 3) << 3) + (px >> 3);
                int rw = ((win & 7) << 3) + (px & 7);
                int p = (rh + 4) & 63;
                int qq = (rw + 4) & 63;
                featb[((size_t)(bidx * 64 + p) * 64 + qq) * 256 + f] =
                    pack1_bf16(acc[mf][nf][j] + bias);
            }
        }
    }
}

// ---------------------------------------------------------------------------
// K5: fused bilinear-sample + conv via bf16 MFMA implicit GEMM (unchanged).
// ---------------------------------------------------------------------------
__global__ __launch_bounds__(256) void sample_conv_mfma_kernel(
    const unsigned short* __restrict__ featb, const float* __restrict__ ymap,
    const unsigned short* __restrict__ wT2, const float* __restrict__ dsc_b,
    float* __restrict__ out) {

    __shared__ __align__(16) char Asb[8192];
    __shared__ __align__(16) char Bsb[32768];
    __shared__ unsigned row0[9][64];
    __shared__ unsigned row1[9][64];
    __shared__ float    wyv[9][64];

    int blk = blockIdx.x;              // 0..511 = b*64 + wd
    int b = blk >> 6, wd = blk & 63;
    int tid = threadIdx.x;
    int lane = tid & 63, w = tid >> 6;

    for (int idx = tid; idx < 576; idx += 256) {
        int k = idx >> 6, hd = idx & 63;
        float y = ymap[((size_t)(b * 576 + wd * 9 + k)) * 64 + hd];
        y = fminf(fmaxf(y, 0.0f), 63.0f);
        float y0f = floorf(y);
        int y0 = (int)y0f;
        int y1 = min(y0 + 1, 63);
        int xc = min(max(hd + k - 4, 0), 63);
        row0[k][hd] = (unsigned)(((b * 64 + y0) * 64 + xc) * 512);
        row1[k][hd] = (unsigned)(((b * 64 + y1) * 64 + xc) * 512);
        wyv[k][hd] = y - y0f;
    }

    f32x4 acc[4][4];
    #pragma unroll
    for (int m = 0; m < 4; ++m)
        #pragma unroll
        for (int n = 0; n < 4; ++n) {
            f32x4 z = {0.0f, 0.0f, 0.0f, 0.0f};
            acc[m][n] = z;
        }

    const char* featc = (const char*)featb;
    const char* wc    = (const char*)wT2;

    int pxA0 = tid >> 3;
    int sA   = tid & 7;
    int rA = (lane & 15) * 128;
    int u0 = (((lane >> 4)    ) ^ (lane & 7)) << 4;
    int u1 = ((4 + (lane >> 4)) ^ (lane & 7)) << 4;

    __syncthreads();

    for (int c = 0; c < 36; ++c) {
        #pragma unroll
        for (int r = 0; r < 8; ++r) {
            int pos = r * 256 + tid;
            int n = pos >> 3, uu = pos & 7;
            int s = uu ^ (n & 7);
            const char* src = wc + n * 4608 + c * 128 + s * 16;
            __builtin_amdgcn_global_load_lds(
                (const __attribute__((address_space(1))) unsigned int*)src,
                (__attribute__((address_space(3))) unsigned int*)(Bsb + pos * 16),
                16, 0, 0);
        }
        int ks  = c >> 2;
        int cib = (c & 3) * 128;
        #pragma unroll
        for (int r = 0; r < 2; ++r) {
            int px = pxA0 + r * 32;
            unsigned b0 = row0[ks][px] + cib + sA * 16;
            unsigned b1 = row1[ks][px] + cib + sA * 16;
            float wy = wyv[ks][px];
            float om = 1.0f - wy;
            uint4 v0 = *(const uint4*)(featc + b0);
            uint4 v1 = *(const uint4*)(featc + b1);
            const unsigned* q0 = (const unsigned*)&v0;
            const unsigned* q1 = (const unsigned*)&v1;
            uint4 o4;
            unsigned* qo = (unsigned*)&o4;
            #pragma unroll
            for (int j = 0; j < 4; ++j) {
                union { unsigned u; float f; } alo, ahi, blo, bhi;
                alo.u = q0[j] << 16; ahi.u = q0[j] & 0xFFFF0000u;
                blo.u = q1[j] << 16; bhi.u = q1[j] & 0xFFFF0000u;
                float rlo = alo.f * om + blo.f * wy;
                float rhi = ahi.f * om + bhi.f * wy;
                qo[j] = pack2_bf16(rlo, rhi);
            }
            *(uint4*)(Asb + px * 128 + ((sA ^ (px & 7)) << 4)) = o4;
        }
        __syncthreads();

        bf16x8 av[4][2], bv[4][2];
        #pragma unroll
        for (int m = 0; m < 4; ++m) {
            av[m][0] = *(const bf16x8*)(Asb + m * 2048 + rA + u0);
            av[m][1] = *(const bf16x8*)(Asb + m * 2048 + rA + u1);
        }
        #pragma unroll
        for (int n = 0; n < 4; ++n) {
            bv[n][0] = *(const bf16x8*)(Bsb + w * 8192 + n * 2048 + rA + u0);
            bv[n][1] = *(const bf16x8*)(Bsb + w * 8192 + n * 2048 + rA + u1);
        }
        #pragma unroll
        for (int m = 0; m < 4; ++m)
            #pragma unroll
            for (int n = 0; n < 4; ++n) {
                acc[m][n] = __builtin_amdgcn_mfma_f32_16x16x32_bf16(av[m][0], bv[n][0], acc[m][n], 0, 0, 0);
                acc[m][n] = __builtin_amdgcn_mfma_f32_16x16x32_bf16(av[m][1], bv[n][1], acc[m][n], 0, 0, 0);
            }
        __syncthreads();
    }

    #pragma unroll
    for (int n = 0; n < 4; ++n) {
        int o = w * 64 + n * 16 + (lane & 15);
        float bvs = dsc_b[o];
        float* orow = out + ((size_t)(b * 256 + o) * 64 + wd) * 64;
        #pragma unroll
        for (int m = 0; m < 4; ++m) {
            int px = m * 16 + (lane >> 4) * 4;
            float4 res;
            res.x = fmaxf(acc[m][n][0] + bvs, 0.0f);
            res.y = fmaxf(acc[m][n][1] + bvs, 0.0f);
            res.z = fmaxf(acc[m][n][2] + bvs, 0.0f);
            res.w = fmaxf(acc[m][n][3] + bvs, 0.0f);
            *(float4*)(orow + px) = res;
        }
    }
}

// ---------------------------------------------------------------------------
extern "C" void kernel_launch(void* const* d_in, const int* in_sizes, int n_in,
                              void* d_out, int out_size, void* d_ws, size_t ws_size,
                              hipStream_t stream) {
    (void)in_sizes; (void)n_in; (void)out_size; (void)ws_size;
    const float* x        = (const float*)d_in[0];
    const float* qkv_w    = (const float*)d_in[1];
    const float* qkv_b    = (const float*)d_in[2];
    const float* proj_w   = (const float*)d_in[3];
    const float* proj_b   = (const float*)d_in[4];
    const float* rel_bias = (const float*)d_in[5];
    const float* offset   = (const float*)d_in[6];
    const float* dsc_w    = (const float*)d_in[7];
    const float* dsc_b    = (const float*)d_in[8];
    float* out = (float*)d_out;

    float* ws     = (float*)d_ws;
    float* qb     = ws;                                   // 8.39M f32
    float* kb     = qb + NFLOAT_BUF;
    float* vb     = kb + NFLOAT_BUF;
    unsigned short* attn_ob = (unsigned short*)(vb + NFLOAT_BUF);   // 8.39M bf16
    unsigned short* featb   = attn_ob + NFLOAT_BUF;                 // 8.39M bf16
    unsigned short* xb      = featb + NFLOAT_BUF;                   // 8.39M bf16
    unsigned short* wb      = xb + NFLOAT_BUF;                      // 196608 bf16
    unsigned short* pwb     = wb + 196608;                          // 65536 bf16
    unsigned short* wT2     = pwb + 65536;                          // 589824 bf16
    float* ymap   = (float*)(wT2 + 589824);                         // 294912 f32

    cvt_bf16_kernel<<<4096, 256, 0, stream>>>(x, xb, 1048576);
    cvt_bf16_kernel<<<96, 256, 0, stream>>>(qkv_w, wb, 24576);
    cvt_bf16_kernel<<<32, 256, 0, stream>>>(proj_w, pwb, 8192);
    transpose_w_kernel<<<2304, 256, 0, stream>>>(dsc_w, wT2);
    ymap_kernel<<<128, 256, 0, stream>>>(offset, ymap);
    qkv_mfma_kernel<<<dim3(3, 512), 256, 0, stream>>>(xb, wb, qkv_b, qb, kb, vb);
    attn_kernel<<<512, 256, 0, stream>>>(qb, kb, vb, rel_bias, attn_ob);
    proj_mfma_kernel<<<512, 256, 0, stream>>>(attn_ob, pwb, proj_b, featb);
    sample_conv_mfma_kernel<<<512, 256, 0, stream>>>(featb, ymap, wT2, dsc_b, out);
}

// Round 4
// 225.161 us; speedup vs baseline: 5.0615x; 1.4876x over previous
//
#include <hip/hip_runtime.h>
#include <math.h>

// Shapes: B=8, H=W=64, C=256, HEADS=8, d=32, WS=8, SS=4, K=9
// NTOK = 32768 tokens; 512 windows of 64 tokens.
// Conv = implicit GEMM: M=32768 px, N=256 oc, K=2304 (bf16 MFMA).
// QKV  = GEMM M=32768, N=768, K=256 (bf16 MFMA, fp16 outputs).
// Attn = per-window MFMA fp16: S^T = K·Q^T, O = P·V^T. 1 wave = 1 head.
// Proj = GEMM M=32768, N=256, K=256 (bf16 MFMA).

#define NFLOAT_BUF 8388608  // 32768*256

typedef float f32x4 __attribute__((ext_vector_type(4)));
typedef __bf16 bf16x8 __attribute__((ext_vector_type(8)));
typedef _Float16 f16x8 __attribute__((ext_vector_type(8)));

__device__ inline unsigned pack2_bf16(float a, float b) {
    union { float f; unsigned u; } ua, ub;
    ua.f = a; ub.f = b;
    unsigned ra = (ua.u + 0x7FFFu + ((ua.u >> 16) & 1u)) >> 16;
    unsigned rb = (ub.u + 0x7FFFu + ((ub.u >> 16) & 1u)) & 0xFFFF0000u;
    return (ra & 0xFFFFu) | rb;
}
__device__ inline unsigned short pack1_bf16(float a) {
    union { float f; unsigned u; } v;
    v.f = a;
    return (unsigned short)((v.u + 0x7FFFu + ((v.u >> 16) & 1u)) >> 16);
}

// ---------------------------------------------------------------------------
// fp32 -> bf16 bulk convert (8 elems/thread)
// ---------------------------------------------------------------------------
__global__ __launch_bounds__(256) void cvt_bf16_kernel(const float* __restrict__ src,
                                                       unsigned short* __restrict__ dst,
                                                       int n8) {
    int t = blockIdx.x * 256 + threadIdx.x;
    if (t >= n8) return;
    const float4* s = (const float4*)(src + (size_t)t * 8);
    float4 a = s[0], b = s[1];
    uint4 o;
    o.x = pack2_bf16(a.x, a.y); o.y = pack2_bf16(a.z, a.w);
    o.z = pack2_bf16(b.x, b.y); o.w = pack2_bf16(b.z, b.w);
    *(uint4*)(dst + (size_t)t * 8) = o;
}

// ---------------------------------------------------------------------------
// dsc_weight (O=256, I=256, K=9) -> wT2 bf16 [o][kk=k*256+i]
// ---------------------------------------------------------------------------
__global__ __launch_bounds__(256) void transpose_w_kernel(const float* __restrict__ w,
                                                          unsigned short* __restrict__ wT) {
    int t = blockIdx.x * 256 + threadIdx.x;   // < 589824
    int o = t / 2304;
    int kk = t - o * 2304;
    int k = kk >> 8, i = kk & 255;
    wT[t] = pack1_bf16(w[(o * 256 + i) * 9 + k]);
}

// ---------------------------------------------------------------------------
// snake coordinate map -> ymap[b][wd*9+k][hd]
// ---------------------------------------------------------------------------
__global__ __launch_bounds__(256) void ymap_kernel(const float* __restrict__ offset,
                                                   float* __restrict__ ymap) {
    int t = blockIdx.x * 256 + threadIdx.x;   // < 32768
    int hd = t & 63;
    int wd = (t >> 6) & 63;
    int b  = t >> 12;
    const float* op = offset + ((size_t)(b * 18) * 64 + wd) * 64 + hd;
    float yo[9];
    #pragma unroll
    for (int k = 0; k < 9; ++k) yo[k] = op[(size_t)k * 4096];
    float cum[9];
    cum[4] = 0.0f;
    float s = 0.0f;
    for (int j = 3; j >= 0; --j) { s += yo[j]; cum[j] = s; }
    s = 0.0f;
    for (int j = 5; j < 9; ++j) { s += yo[j]; cum[j] = s; }
    float wdf = (float)wd;
    float* yp = ymap + ((size_t)(b * 576 + wd * 9)) * 64 + hd;
    #pragma unroll
    for (int k = 0; k < 9; ++k) yp[(size_t)k * 64] = wdf + cum[k];
}

// ---------------------------------------------------------------------------
// QKV GEMM via bf16 MFMA. Block = 64 M-rows x 256 N. grid (3, 512).
// Outputs fp16: q,k as [win*8+h][l][32]; v transposed [win*8+h][32][64].
// ---------------------------------------------------------------------------
__global__ __launch_bounds__(256) void qkv_mfma_kernel(
    const unsigned short* __restrict__ xb, const unsigned short* __restrict__ wb,
    const float* __restrict__ qkv_b,
    _Float16* __restrict__ qh, _Float16* __restrict__ kh, _Float16* __restrict__ vt) {

    __shared__ __align__(16) char Asb[8192];    // 64 rows * 128B
    __shared__ __align__(16) char Bsb[32768];   // 256 rows * 128B
    __shared__ unsigned rowoff[64];

    int nb = blockIdx.x;          // 0..2  (q / k / v)
    int m0 = blockIdx.y * 64;
    int tid = threadIdx.x;
    int lane = tid & 63, w = tid >> 6;
    int gw = m0 >> 6;             // global window

    if (tid < 64) {
        int l = tid;
        int b = gw >> 6, win = gw & 63;
        int rh = ((win >> 3) << 3) + (l >> 3);
        int rw = ((win & 7) << 3) + (l & 7);
        int sh = (rh + 4) & 63, sw = (rw + 4) & 63;
        rowoff[l] = (unsigned)(((b * 64 + sh) * 64 + sw) * 512);  // byte offset
    }

    f32x4 acc[4][4];
    #pragma unroll
    for (int m = 0; m < 4; ++m)
        #pragma unroll
        for (int n = 0; n < 4; ++n) {
            f32x4 z = {0.0f, 0.0f, 0.0f, 0.0f};
            acc[m][n] = z;
        }

    const char* xc = (const char*)xb;
    const char* wc = (const char*)wb;
    int rA = (lane & 15) * 128;
    int u0 = (((lane >> 4)    ) ^ (lane & 7)) << 4;
    int u1 = ((4 + (lane >> 4)) ^ (lane & 7)) << 4;

    __syncthreads();

    for (int c = 0; c < 4; ++c) {   // K chunks of 64
        #pragma unroll
        for (int r = 0; r < 2; ++r) {
            int pos = r * 256 + tid;
            int row = pos >> 3, u = pos & 7;
            const char* src = xc + rowoff[row] + c * 128 + ((u ^ (row & 7)) << 4);
            __builtin_amdgcn_global_load_lds(
                (const __attribute__((address_space(1))) unsigned int*)src,
                (__attribute__((address_space(3))) unsigned int*)(Asb + pos * 16),
                16, 0, 0);
        }
        #pragma unroll
        for (int r = 0; r < 8; ++r) {
            int pos = r * 256 + tid;
            int n = pos >> 3, u = pos & 7;
            const char* src = wc + (size_t)(nb * 256 + n) * 512 + c * 128 + ((u ^ (n & 7)) << 4);
            __builtin_amdgcn_global_load_lds(
                (const __attribute__((address_space(1))) unsigned int*)src,
                (__attribute__((address_space(3))) unsigned int*)(Bsb + pos * 16),
                16, 0, 0);
        }
        __syncthreads();

        bf16x8 av[4][2], bv[4][2];
        #pragma unroll
        for (int m = 0; m < 4; ++m) {
            av[m][0] = *(const bf16x8*)(Asb + m * 2048 + rA + u0);
            av[m][1] = *(const bf16x8*)(Asb + m * 2048 + rA + u1);
        }
        #pragma unroll
        for (int n = 0; n < 4; ++n) {
            bv[n][0] = *(const bf16x8*)(Bsb + w * 8192 + n * 2048 + rA + u0);
            bv[n][1] = *(const bf16x8*)(Bsb + w * 8192 + n * 2048 + rA + u1);
        }
        #pragma unroll
        for (int m = 0; m < 4; ++m)
            #pragma unroll
            for (int n = 0; n < 4; ++n) {
                acc[m][n] = __builtin_amdgcn_mfma_f32_16x16x32_bf16(av[m][0], bv[n][0], acc[m][n], 0, 0, 0);
                acc[m][n] = __builtin_amdgcn_mfma_f32_16x16x32_bf16(av[m][1], bv[n][1], acc[m][n], 0, 0, 0);
            }
        __syncthreads();
    }

    float scale = (nb == 0) ? 0.17677669529663689f : 1.0f;
    #pragma unroll
    for (int nf = 0; nf < 4; ++nf) {
        int o = w * 64 + nf * 16 + (lane & 15);
        float bias = qkv_b[nb * 256 + o];
        int hh = o >> 5, dd = o & 31;
        if (nb < 2) {
            _Float16* dstb = (nb == 0) ? qh : kh;
            _Float16* base = dstb + ((size_t)(gw * 8 + hh) * 64) * 32 + dd;
            #pragma unroll
            for (int mf = 0; mf < 4; ++mf) {
                int l0 = mf * 16 + (lane >> 4) * 4;
                #pragma unroll
                for (int j = 0; j < 4; ++j)
                    base[(size_t)(l0 + j) * 32] = (_Float16)((acc[mf][nf][j] + bias) * scale);
            }
        } else {
            _Float16* base = vt + ((size_t)(gw * 8 + hh) * 32 + dd) * 64;
            #pragma unroll
            for (int mf = 0; mf < 4; ++mf) {
                int l0 = mf * 16 + (lane >> 4) * 4;
                union { _Float16 x[4]; uint2 u; } pk;
                #pragma unroll
                for (int j = 0; j < 4; ++j) pk.x[j] = (_Float16)(acc[mf][nf][j] + bias);
                *(uint2*)(base + l0) = pk.u;
            }
        }
    }
}

// ---------------------------------------------------------------------------
// Attention via fp16 MFMA. Block = 1 window, 512 threads = 8 waves = 8 heads.
// No inter-wave communication (zero __syncthreads).
// S^T = mfma(K, Q): C col=query, row=key -> lane holds 16 keys for 1 query.
// Softmax: 16 VALU + shfl_xor(16,32). P -> swizzled LDS (8KB/wave).
// O = mfma(P, V^T): C col=d, row=query. Epilogue: bf16 attn_ob.
// ---------------------------------------------------------------------------
__global__ __launch_bounds__(512) void attn_mfma_kernel(
    const _Float16* __restrict__ qh, const _Float16* __restrict__ kh,
    const _Float16* __restrict__ vt, const float* __restrict__ rel_bias,
    unsigned short* __restrict__ attn_ob) {

    __shared__ __align__(16) char Plds[65536];   // 8 waves x 64 rows x 128B
    int n = blockIdx.x;
    int win = n & 63;
    int wy = win >> 3, wx = win & 7;
    int tid = threadIdx.x, lane = tid & 63, h = tid >> 6;
    int qc = lane & 15, g = lane >> 4;
    char* P = Plds + h * 8192;

    const _Float16* qp = qh + (size_t)(n * 8 + h) * 2048;
    const _Float16* kp = kh + (size_t)(n * 8 + h) * 2048;
    const _Float16* vp = vt + (size_t)(n * 8 + h) * 2048;
    const float* rb = rel_bias + (size_t)h * 4096;

    // region codes for this lane's 16 keys: key = mt*16 + g*4 + j
    int rk[16];
    #pragma unroll
    for (int mt = 0; mt < 4; ++mt)
        #pragma unroll
        for (int j = 0; j < 4; ++j) {
            int key = mt * 16 + g * 4 + j;
            int rh = wy * 8 + (key >> 3), rw = wx * 8 + (key & 7);
            rk[mt * 4 + j] = (rh < 56 ? 0 : (rh < 60 ? 1 : 2)) * 3
                           + (rw < 56 ? 0 : (rw < 60 ? 1 : 2));
        }

    f16x8 kf[4];
    #pragma unroll
    for (int mt = 0; mt < 4; ++mt)
        kf[mt] = *(const f16x8*)(kp + (mt * 16 + qc) * 32 + g * 8);

    #pragma unroll
    for (int nt = 0; nt < 4; ++nt) {
        int q = nt * 16 + qc;
        int rqh = wy * 8 + (q >> 3), rqw = wx * 8 + (q & 7);
        int rq = (rqh < 56 ? 0 : (rqh < 60 ? 1 : 2)) * 3
               + (rqw < 56 ? 0 : (rqw < 60 ? 1 : 2));
        f16x8 qf = *(const f16x8*)(qp + q * 32 + g * 8);

        f32x4 s[4];
        #pragma unroll
        for (int mt = 0; mt < 4; ++mt) {
            f32x4 z = {0.0f, 0.0f, 0.0f, 0.0f};
            s[mt] = __builtin_amdgcn_mfma_f32_16x16x32_f16(kf[mt], qf, z, 0, 0, 0);
        }

        float vals[16];
        #pragma unroll
        for (int mt = 0; mt < 4; ++mt) {
            float4 bv4 = *(const float4*)(rb + q * 64 + mt * 16 + g * 4);
            vals[mt * 4 + 0] = s[mt][0] + bv4.x + (rk[mt * 4 + 0] != rq ? -100.0f : 0.0f);
            vals[mt * 4 + 1] = s[mt][1] + bv4.y + (rk[mt * 4 + 1] != rq ? -100.0f : 0.0f);
            vals[mt * 4 + 2] = s[mt][2] + bv4.z + (rk[mt * 4 + 2] != rq ? -100.0f : 0.0f);
            vals[mt * 4 + 3] = s[mt][3] + bv4.w + (rk[mt * 4 + 3] != rq ? -100.0f : 0.0f);
        }

        float mx = vals[0];
        #pragma unroll
        for (int i = 1; i < 16; ++i) mx = fmaxf(mx, vals[i]);
        mx = fmaxf(mx, __shfl_xor(mx, 16));
        mx = fmaxf(mx, __shfl_xor(mx, 32));

        float sum = 0.0f;
        #pragma unroll
        for (int i = 0; i < 16; ++i) { vals[i] = __expf(vals[i] - mx); sum += vals[i]; }
        sum += __shfl_xor(sum, 16);
        sum += __shfl_xor(sum, 32);
        float inv = 1.0f / sum;

        #pragma unroll
        for (int mt = 0; mt < 4; ++mt) {
            union { _Float16 x[4]; uint2 u; } pk4;
            #pragma unroll
            for (int j = 0; j < 4; ++j) pk4.x[j] = (_Float16)(vals[mt * 4 + j] * inv);
            int off = (mt * 32 + g * 8) ^ ((q & 7) << 4);
            *(uint2*)(P + q * 128 + off) = pk4.u;
        }
    }

    // PV: O = P (q x key) * V^T rows (d x key)
    f16x8 pa[4][2];
    #pragma unroll
    for (int im = 0; im < 4; ++im)
        #pragma unroll
        for (int ks = 0; ks < 2; ++ks) {
            int row = im * 16 + qc;
            int off = (ks * 64 + g * 16) ^ ((row & 7) << 4);
            pa[im][ks] = *(const f16x8*)(P + row * 128 + off);
        }
    f16x8 bvv[2][2];
    #pragma unroll
    for (int in = 0; in < 2; ++in)
        #pragma unroll
        for (int ks = 0; ks < 2; ++ks)
            bvv[in][ks] = *(const f16x8*)(vp + (in * 16 + qc) * 64 + ks * 32 + g * 8);

    f32x4 acc[4][2];
    #pragma unroll
    for (int im = 0; im < 4; ++im)
        #pragma unroll
        for (int in = 0; in < 2; ++in) {
            f32x4 z = {0.0f, 0.0f, 0.0f, 0.0f};
            acc[im][in] = z;
        }
    #pragma unroll
    for (int im = 0; im < 4; ++im)
        #pragma unroll
        for (int in = 0; in < 2; ++in) {
            acc[im][in] = __builtin_amdgcn_mfma_f32_16x16x32_f16(pa[im][0], bvv[in][0], acc[im][in], 0, 0, 0);
            acc[im][in] = __builtin_amdgcn_mfma_f32_16x16x32_f16(pa[im][1], bvv[in][1], acc[im][in], 0, 0, 0);
        }

    #pragma unroll
    for (int im = 0; im < 4; ++im)
        #pragma unroll
        for (int in = 0; in < 2; ++in)
            #pragma unroll
            for (int j = 0; j < 4; ++j) {
                int q2 = im * 16 + g * 4 + j;
                attn_ob[(size_t)(n * 64 + q2) * 256 + h * 32 + in * 16 + qc] =
                    pack1_bf16(acc[im][in][j]);
            }
}

// ---------------------------------------------------------------------------
// Proj GEMM via bf16 MFMA. Block = 64 M x 256 N. grid 512.
// ---------------------------------------------------------------------------
__global__ __launch_bounds__(256) void proj_mfma_kernel(
    const unsigned short* __restrict__ attn_ob, const unsigned short* __restrict__ pwb,
    const float* __restrict__ proj_b, unsigned short* __restrict__ featb) {

    __shared__ __align__(16) char Asb[8192];
    __shared__ __align__(16) char Bsb[32768];

    int m0 = blockIdx.x * 64;
    int tid = threadIdx.x;
    int lane = tid & 63, w = tid >> 6;
    int gw = m0 >> 6;
    int bidx = gw >> 6, win = gw & 63;

    f32x4 acc[4][4];
    #pragma unroll
    for (int m = 0; m < 4; ++m)
        #pragma unroll
        for (int n = 0; n < 4; ++n) {
            f32x4 z = {0.0f, 0.0f, 0.0f, 0.0f};
            acc[m][n] = z;
        }

    const char* ac = (const char*)attn_ob;
    const char* wc = (const char*)pwb;
    int rA = (lane & 15) * 128;
    int u0 = (((lane >> 4)    ) ^ (lane & 7)) << 4;
    int u1 = ((4 + (lane >> 4)) ^ (lane & 7)) << 4;

    for (int c = 0; c < 4; ++c) {
        #pragma unroll
        for (int r = 0; r < 2; ++r) {
            int pos = r * 256 + tid;
            int row = pos >> 3, u = pos & 7;
            const char* src = ac + (size_t)(m0 + row) * 512 + c * 128 + ((u ^ (row & 7)) << 4);
            __builtin_amdgcn_global_load_lds(
                (const __attribute__((address_space(1))) unsigned int*)src,
                (__attribute__((address_space(3))) unsigned int*)(Asb + pos * 16),
                16, 0, 0);
        }
        #pragma unroll
        for (int r = 0; r < 8; ++r) {
            int pos = r * 256 + tid;
            int n = pos >> 3, u = pos & 7;
            const char* src = wc + (size_t)n * 512 + c * 128 + ((u ^ (n & 7)) << 4);
            __builtin_amdgcn_global_load_lds(
                (const __attribute__((address_space(1))) unsigned int*)src,
                (__attribute__((address_space(3))) unsigned int*)(Bsb + pos * 16),
                16, 0, 0);
        }
        __syncthreads();

        bf16x8 av[4][2], bv[4][2];
        #pragma unroll
        for (int m = 0; m < 4; ++m) {
            av[m][0] = *(const bf16x8*)(Asb + m * 2048 + rA + u0);
            av[m][1] = *(const bf16x8*)(Asb + m * 2048 + rA + u1);
        }
        #pragma unroll
        for (int n = 0; n < 4; ++n) {
            bv[n][0] = *(const bf16x8*)(Bsb + w * 8192 + n * 2048 + rA + u0);
            bv[n][1] = *(const bf16x8*)(Bsb + w * 8192 + n * 2048 + rA + u1);
        }
        #pragma unroll
        for (int m = 0; m < 4; ++m)
            #pragma unroll
            for (int n = 0; n < 4; ++n) {
                acc[m][n] = __builtin_amdgcn_mfma_f32_16x16x32_bf16(av[m][0], bv[n][0], acc[m][n], 0, 0, 0);
                acc[m][n] = __builtin_amdgcn_mfma_f32_16x16x32_bf16(av[m][1], bv[n][1], acc[m][n], 0, 0, 0);
            }
        __syncthreads();
    }

    #pragma unroll
    for (int nf = 0; nf < 4; ++nf) {
        int f = w * 64 + nf * 16 + (lane & 15);
        float bias = proj_b[f];
        #pragma unroll
        for (int mf = 0; mf < 4; ++mf) {
            #pragma unroll
            for (int j = 0; j < 4; ++j) {
                int px = mf * 16 + (lane >> 4) * 4 + j;
                int rh = ((win >> 3) << 3) + (px >> 3);
                int rw = ((win & 7) << 3) + (px & 7);
                int p = (rh + 4) & 63;
                int qq = (rw + 4) & 63;
                featb[((size_t)(bidx * 64 + p) * 64 + qq) * 256 + f] =
                    pack1_bf16(acc[mf][nf][j] + bias);
            }
        }
    }
}

// ---------------------------------------------------------------------------
// Fused bilinear-sample + conv via bf16 MFMA implicit GEMM (unchanged).
// ---------------------------------------------------------------------------
__global__ __launch_bounds__(256) void sample_conv_mfma_kernel(
    const unsigned short* __restrict__ featb, const float* __restrict__ ymap,
    const unsigned short* __restrict__ wT2, const float* __restrict__ dsc_b,
    float* __restrict__ out) {

    __shared__ __align__(16) char Asb[8192];
    __shared__ __align__(16) char Bsb[32768];
    __shared__ unsigned row0[9][64];
    __shared__ unsigned row1[9][64];
    __shared__ float    wyv[9][64];

    int blk = blockIdx.x;              // 0..511 = b*64 + wd
    int b = blk >> 6, wd = blk & 63;
    int tid = threadIdx.x;
    int lane = tid & 63, w = tid >> 6;

    for (int idx = tid; idx < 576; idx += 256) {
        int k = idx >> 6, hd = idx & 63;
        float y = ymap[((size_t)(b * 576 + wd * 9 + k)) * 64 + hd];
        y = fminf(fmaxf(y, 0.0f), 63.0f);
        float y0f = floorf(y);
        int y0 = (int)y0f;
        int y1 = min(y0 + 1, 63);
        int xc = min(max(hd + k - 4, 0), 63);
        row0[k][hd] = (unsigned)(((b * 64 + y0) * 64 + xc) * 512);
        row1[k][hd] = (unsigned)(((b * 64 + y1) * 64 + xc) * 512);
        wyv[k][hd] = y - y0f;
    }

    f32x4 acc[4][4];
    #pragma unroll
    for (int m = 0; m < 4; ++m)
        #pragma unroll
        for (int n = 0; n < 4; ++n) {
            f32x4 z = {0.0f, 0.0f, 0.0f, 0.0f};
            acc[m][n] = z;
        }

    const char* featc = (const char*)featb;
    const char* wc    = (const char*)wT2;

    int pxA0 = tid >> 3;
    int sA   = tid & 7;
    int rA = (lane & 15) * 128;
    int u0 = (((lane >> 4)    ) ^ (lane & 7)) << 4;
    int u1 = ((4 + (lane >> 4)) ^ (lane & 7)) << 4;

    __syncthreads();

    for (int c = 0; c < 36; ++c) {
        #pragma unroll
        for (int r = 0; r < 8; ++r) {
            int pos = r * 256 + tid;
            int n = pos >> 3, uu = pos & 7;
            int s = uu ^ (n & 7);
            const char* src = wc + n * 4608 + c * 128 + s * 16;
            __builtin_amdgcn_global_load_lds(
                (const __attribute__((address_space(1))) unsigned int*)src,
                (__attribute__((address_space(3))) unsigned int*)(Bsb + pos * 16),
                16, 0, 0);
        }
        int ks  = c >> 2;
        int cib = (c & 3) * 128;
        #pragma unroll
        for (int r = 0; r < 2; ++r) {
            int px = pxA0 + r * 32;
            unsigned b0 = row0[ks][px] + cib + sA * 16;
            unsigned b1 = row1[ks][px] + cib + sA * 16;
            float wy = wyv[ks][px];
            float om = 1.0f - wy;
            uint4 v0 = *(const uint4*)(featc + b0);
            uint4 v1 = *(const uint4*)(featc + b1);
            const unsigned* q0 = (const unsigned*)&v0;
            const unsigned* q1 = (const unsigned*)&v1;
            uint4 o4;
            unsigned* qo = (unsigned*)&o4;
            #pragma unroll
            for (int j = 0; j < 4; ++j) {
                union { unsigned u; float f; } alo, ahi, blo, bhi;
                alo.u = q0[j] << 16; ahi.u = q0[j] & 0xFFFF0000u;
                blo.u = q1[j] << 16; bhi.u = q1[j] & 0xFFFF0000u;
                float rlo = alo.f * om + blo.f * wy;
                float rhi = ahi.f * om + bhi.f * wy;
                qo[j] = pack2_bf16(rlo, rhi);
            }
            *(uint4*)(Asb + px * 128 + ((sA ^ (px & 7)) << 4)) = o4;
        }
        __syncthreads();

        bf16x8 av[4][2], bv[4][2];
        #pragma unroll
        for (int m = 0; m < 4; ++m) {
            av[m][0] = *(const bf16x8*)(Asb + m * 2048 + rA + u0);
            av[m][1] = *(const bf16x8*)(Asb + m * 2048 + rA + u1);
        }
        #pragma unroll
        for (int n = 0; n < 4; ++n) {
            bv[n][0] = *(const bf16x8*)(Bsb + w * 8192 + n * 2048 + rA + u0);
            bv[n][1] = *(const bf16x8*)(Bsb + w * 8192 + n * 2048 + rA + u1);
        }
        #pragma unroll
        for (int m = 0; m < 4; ++m)
            #pragma unroll
            for (int n = 0; n < 4; ++n) {
                acc[m][n] = __builtin_amdgcn_mfma_f32_16x16x32_bf16(av[m][0], bv[n][0], acc[m][n], 0, 0, 0);
                acc[m][n] = __builtin_amdgcn_mfma_f32_16x16x32_bf16(av[m][1], bv[n][1], acc[m][n], 0, 0, 0);
            }
        __syncthreads();
    }

    #pragma unroll
    for (int n = 0; n < 4; ++n) {
        int o = w * 64 + n * 16 + (lane & 15);
        float bvs = dsc_b[o];
        float* orow = out + ((size_t)(b * 256 + o) * 64 + wd) * 64;
        #pragma unroll
        for (int m = 0; m < 4; ++m) {
            int px = m * 16 + (lane >> 4) * 4;
            float4 res;
            res.x = fmaxf(acc[m][n][0] + bvs, 0.0f);
            res.y = fmaxf(acc[m][n][1] + bvs, 0.0f);
            res.z = fmaxf(acc[m][n][2] + bvs, 0.0f);
            res.w = fmaxf(acc[m][n][3] + bvs, 0.0f);
            *(float4*)(orow + px) = res;
        }
    }
}

// ---------------------------------------------------------------------------
extern "C" void kernel_launch(void* const* d_in, const int* in_sizes, int n_in,
                              void* d_out, int out_size, void* d_ws, size_t ws_size,
                              hipStream_t stream) {
    (void)in_sizes; (void)n_in; (void)out_size; (void)ws_size;
    const float* x        = (const float*)d_in[0];
    const float* qkv_w    = (const float*)d_in[1];
    const float* qkv_b    = (const float*)d_in[2];
    const float* proj_w   = (const float*)d_in[3];
    const float* proj_b   = (const float*)d_in[4];
    const float* rel_bias = (const float*)d_in[5];
    const float* offset   = (const float*)d_in[6];
    const float* dsc_w    = (const float*)d_in[7];
    const float* dsc_b    = (const float*)d_in[8];
    float* out = (float*)d_out;

    unsigned short* wsu = (unsigned short*)d_ws;
    _Float16* qh = (_Float16*)wsu;                                  // 8.39M fp16
    _Float16* kh = (_Float16*)(wsu + NFLOAT_BUF);
    _Float16* vt = (_Float16*)(wsu + 2 * (size_t)NFLOAT_BUF);
    unsigned short* attn_ob = wsu + 3 * (size_t)NFLOAT_BUF;         // bf16
    unsigned short* featb   = wsu + 4 * (size_t)NFLOAT_BUF;         // bf16
    unsigned short* xb      = wsu + 5 * (size_t)NFLOAT_BUF;         // bf16
    unsigned short* wb      = wsu + 6 * (size_t)NFLOAT_BUF;         // 196608 bf16
    unsigned short* pwb     = wb + 196608;                          // 65536 bf16
    unsigned short* wT2     = pwb + 65536;                          // 589824 bf16
    float* ymap = (float*)(wT2 + 589824);                           // 294912 f32

    cvt_bf16_kernel<<<4096, 256, 0, stream>>>(x, xb, 1048576);
    cvt_bf16_kernel<<<96, 256, 0, stream>>>(qkv_w, wb, 24576);
    cvt_bf16_kernel<<<32, 256, 0, stream>>>(proj_w, pwb, 8192);
    transpose_w_kernel<<<2304, 256, 0, stream>>>(dsc_w, wT2);
    ymap_kernel<<<128, 256, 0, stream>>>(offset, ymap);
    qkv_mfma_kernel<<<dim3(3, 512), 256, 0, stream>>>(xb, wb, qkv_b, qh, kh, vt);
    attn_mfma_kernel<<<512, 512, 0, stream>>>(qh, kh, vt, rel_bias, attn_ob);
    proj_mfma_kernel<<<512, 256, 0, stream>>>(attn_ob, pwb, proj_b, featb);
    sample_conv_mfma_kernel<<<512, 256, 0, stream>>>(featb, ymap, wT2, dsc_b, out);
}